// Round 10
// baseline (226.009 us; speedup 1.0000x reference)
//
#include <hip/hip_runtime.h>
#include <hip/hip_bf16.h>
#include <stdint.h>

#define NN 4096
#define NF 128
#define XROWS 4

using f32x4  = __attribute__((ext_vector_type(4))) float;
using bf16x8 = __attribute__((ext_vector_type(8))) __bf16;
using u16x8  = __attribute__((ext_vector_type(8))) uint16_t;

__device__ __forceinline__ uint16_t f2b(float f) {
    union { float f; uint32_t u; } v; v.f = f;
    uint32_t r = v.u + 0x7FFFu + ((v.u >> 16) & 1u);
    return (uint16_t)(r >> 16);
}

__device__ __forceinline__ float b2f(uint16_t u) {
    union { uint32_t u; float f; } v; v.u = ((uint32_t)u) << 16;
    return v.f;
}

// ---------------------------------------------------------------------------
// Kernel 1: XW = X@W (4 rows/block), s_col/s_row scores, XWT bf16 (ushort4 store)
// ---------------------------------------------------------------------------
__global__ __launch_bounds__(128) void xw_kernel(
    const float* __restrict__ X, const float* __restrict__ W,
    const float* __restrict__ a,
    uint16_t* __restrict__ XWT,
    float* __restrict__ s_col, float* __restrict__ s_row) {
    __shared__ float xs[XROWS][NF];
    __shared__ float red[XROWS][2][2];
    const int i0 = blockIdx.x * XROWS, f = threadIdx.x;
    #pragma unroll
    for (int r = 0; r < XROWS; ++r) xs[r][f] = X[(size_t)(i0 + r) * NF + f];
    __syncthreads();
    float acc[XROWS] = {0.f, 0.f, 0.f, 0.f};
    #pragma unroll 4
    for (int k = 0; k < NF; ++k) {
        const float w = W[k * NF + f];
        #pragma unroll
        for (int r = 0; r < XROWS; ++r) acc[r] += xs[r][k] * w;
    }
    ushort4 xo;
    xo.x = f2b(acc[0]); xo.y = f2b(acc[1]); xo.z = f2b(acc[2]); xo.w = f2b(acc[3]);
    *(ushort4*)(XWT + (size_t)f * NN + i0) = xo;
    const float a1 = a[f], a2 = a[NF + f];
    #pragma unroll
    for (int r = 0; r < XROWS; ++r) {
        float sc = acc[r] * a1;
        float sr = acc[r] * a2;
        #pragma unroll
        for (int off = 32; off; off >>= 1) {
            sc += __shfl_down(sc, off);
            sr += __shfl_down(sr, off);
        }
        if ((f & 63) == 0) { red[r][f >> 6][0] = sc; red[r][f >> 6][1] = sr; }
    }
    __syncthreads();
    if (f < XROWS) {
        s_col[i0 + f] = red[f][0][0] + red[f][1][0];
        s_row[i0 + f] = red[f][0][1] + red[f][1][1];
    }
}

// ---------------------------------------------------------------------------
// Kernel 2: prep — brute-force order statistics (O(N^2) counting, fully parallel)
// ---------------------------------------------------------------------------
__global__ __launch_bounds__(256) void prep_kernel(
    const float* __restrict__ s_row, const float* __restrict__ s_col,
    int* __restrict__ ks, float* __restrict__ w1s, float* __restrict__ w2s,
    float4* __restrict__ rec) {
    __shared__ __align__(16) float sr[NN];
    const int t = threadIdx.x;
    #pragma unroll
    for (int c = 0; c < 16; ++c) sr[t + c * 256] = s_row[t + c * 256];
    __syncthreads();
    const bool isC = blockIdx.x >= 128;
    const int tgt = (blockIdx.x & 127) * 32 + (t >> 3);
    const int sub = t & 7;
    const float4* sr4 = (const float4*)sr;
    int cnt = 0;
    if (!isC) {
        const float s = sr[tgt];
        #pragma unroll 4
        for (int q = 0; q < 128; ++q) {
            const int k4 = q * 8 + sub;
            float4 v = sr4[k4];
            const int kb = k4 * 4;
            cnt += (v.x < s) | ((v.x == s) & (kb + 0 < tgt));
            cnt += (v.y < s) | ((v.y == s) & (kb + 1 < tgt));
            cnt += (v.z < s) | ((v.z == s) & (kb + 2 < tgt));
            cnt += (v.w < s) | ((v.w == s) & (kb + 3 < tgt));
        }
    } else {
        const float th = -s_col[tgt];
        #pragma unroll 4
        for (int q = 0; q < 128; ++q) {
            float4 v = sr4[q * 8 + sub];
            cnt += (v.x <= th) + (v.y <= th) + (v.z <= th) + (v.w <= th);
        }
    }
    cnt += __shfl_down(cnt, 4);
    cnt += __shfl_down(cnt, 2);
    cnt += __shfl_down(cnt, 1);
    if (sub == 0) {
        if (!isC) {
            const float s = sr[tgt];
            ks[cnt]  = tgt;
            w1s[cnt] = __expf(s);
            w2s[cnt] = __expf(0.01f * s);
        } else {
            const float sc = s_col[tgt];
            rec[tgt] = (float4){__int_as_float(cnt), __expf(sc), __expf(0.01f * sc), sc};
        }
    }
}

// ---------------------------------------------------------------------------
// Kernel 3: per-row exact num/att via dual scan (proven round-8 body).
// ---------------------------------------------------------------------------
#define PB(b) ((b) + (((b) >> 4) << 1))

__global__ __launch_bounds__(512, 8) void row_kernel(
    const float* __restrict__ A,
    const float* __restrict__ s_row,
    const int* __restrict__ ks, const float* __restrict__ w1s, const float* __restrict__ w2s,
    const float4* __restrict__ rec,
    uint16_t* __restrict__ att) {
    __shared__ __align__(16) float rowA[NN];
    __shared__ __align__(16) uint16_t S1[4640];
    __shared__ __align__(16) uint16_t S2[4640];
    __shared__ float wtot[2][8];
    const int i = blockIdx.x, t = threadIdx.x;

    {
        const float4* Ar = (const float4*)(A + (size_t)i * NN);
        #pragma unroll
        for (int c = 0; c < 2; ++c)
            ((float4*)rowA)[t + c * 512] = Ar[t + c * 512];
    }
    __syncthreads();

    float l1[8], l2[8];
    {
        const int4*   k4 = (const int4*)ks;
        const float4* a4 = (const float4*)w1s;
        const float4* b4 = (const float4*)w2s;
        float run1 = 0.f, run2 = 0.f;
        #pragma unroll
        for (int g = 0; g < 2; ++g) {
            int4   kk = k4[2 * t + g];
            float4 wa = a4[2 * t + g];
            float4 wb = b4[2 * t + g];
            float g0 = rowA[kk.x], g1 = rowA[kk.y], g2 = rowA[kk.z], g3 = rowA[kk.w];
            run1 += g0 * wa.x; l1[4 * g + 0] = run1;  run2 += g0 * wb.x; l2[4 * g + 0] = run2;
            run1 += g1 * wa.y; l1[4 * g + 1] = run1;  run2 += g1 * wb.y; l2[4 * g + 1] = run2;
            run1 += g2 * wa.z; l1[4 * g + 2] = run1;  run2 += g2 * wb.z; l2[4 * g + 2] = run2;
            run1 += g3 * wa.w; l1[4 * g + 3] = run1;  run2 += g3 * wb.w; l2[4 * g + 3] = run2;
        }
    }
    float s1 = l1[7], s2 = l2[7];
    const int lane = t & 63, wid = t >> 6;
    #pragma unroll
    for (int off = 1; off < 64; off <<= 1) {
        float u1 = __shfl_up(s1, off);
        float u2 = __shfl_up(s2, off);
        if (lane >= off) { s1 += u1; s2 += u2; }
    }
    if (lane == 63) { wtot[0][wid] = s1; wtot[1][wid] = s2; }
    __syncthreads();

    float off1 = 0.f, off2 = 0.f, tot1 = 0.f, tot2 = 0.f;
    #pragma unroll
    for (int w = 0; w < 8; ++w) {
        const float va = wtot[0][w], vb = wtot[1][w];
        tot1 += va; tot2 += vb;
        if (w < wid) { off1 += va; off2 += vb; }
    }
    const float ex1 = off1 + s1 - l1[7];
    const float ex2 = off2 + s2 - l2[7];
    {
        uint32_t* q1 = (uint32_t*)S1;
        uint32_t* q2 = (uint32_t*)S2;
        const int qb = t * 4 + (t >> 1);
        #pragma unroll
        for (int m = 0; m < 4; ++m) {
            const float pl1 = m ? l1[2 * m - 1] : 0.f;
            const float pl2 = m ? l2[2 * m - 1] : 0.f;
            const float sa = tot1 - ex1 - pl1;
            const float sb = tot1 - ex1 - l1[2 * m];
            const float pa = ex2 + pl2;
            const float pb = ex2 + l2[2 * m];
            q1[qb + m] = (uint32_t)f2b(sa) | ((uint32_t)f2b(sb) << 16);
            q2[qb + m] = (uint32_t)f2b(pa) | ((uint32_t)f2b(pb) << 16);
        }
    }
    if (t == 511) {
        S1[PB(4096)] = 0;
        S2[PB(4096)] = f2b(tot2);
    }
    __syncthreads();

    const float sri = s_row[i];
    uint32_t* attR = (uint32_t*)(att + (size_t)i * NN);
    #pragma unroll
    for (int e = 0; e < 4; ++e) {
        const int j0 = e * 1024 + 2 * t;
        const float4 ra = rec[j0];
        const float4 rb = rec[j0 + 1];
        const int Ca = __float_as_int(ra.x);
        const int Cb = __float_as_int(rb.x);
        const float numa = ra.y * b2f(S1[PB(Ca)]) + ra.z * b2f(S2[PB(Ca)]);
        const float numb = rb.y * b2f(S1[PB(Cb)]) + rb.z * b2f(S2[PB(Cb)]);
        float za = sri + ra.w; za = za > 0.f ? za : 0.01f * za;
        float zb = sri + rb.w; zb = zb > 0.f ? zb : 0.01f * zb;
        const float dena = __expf(za);
        const float denb = __expf(zb);
        const float va = (numa != 0.f) ? dena * __builtin_amdgcn_rcpf(numa) : 0.f;
        const float vb = (numb != 0.f) ? denb * __builtin_amdgcn_rcpf(numb) : 0.f;
        attR[e * 512 + t] = (uint32_t)f2b(va) | ((uint32_t)f2b(vb) << 16);
    }
}

// ---------------------------------------------------------------------------
// Kernels 4/5: fused skinny GEMM, f-split for occupancy.
// grid (256, 2): blockIdx.x = 16-row tile, blockIdx.y = f-half (64 cols).
// 512 blocks = 2 blocks/CU = 32 waves/CU; launch_bounds(1024,8) caps VGPR<=64.
// Wave w: 16 rows x 64 cols over K-slice [w*256, w*256+256), acc[4].
// acc mapping (verified): row = quad*4+reg, col(frag) = ni*16 + l16.
// ---------------------------------------------------------------------------
__device__ __forceinline__ float gemm16_reduce64(
    float* __restrict__ red, const f32x4 acc[4]) {
    const int t = threadIdx.x;
    const int lane = t & 63, wv = t >> 6;
    const int l16 = lane & 15, quad = lane >> 4;
    float* img = red + (wv & 3) * 1024;
    const int base = l16 * 16 + quad * 4;
    #pragma unroll
    for (int ph = 0; ph < 4; ++ph) {
        if ((wv >> 2) == ph) {
            if (ph == 0) {
                #pragma unroll
                for (int ni = 0; ni < 4; ++ni)
                    *(f32x4*)(img + ni * 256 + base) = acc[ni];
            } else {
                #pragma unroll
                for (int ni = 0; ni < 4; ++ni) {
                    f32x4 x = *(const f32x4*)(img + ni * 256 + base);
                    *(f32x4*)(img + ni * 256 + base) = x + acc[ni];
                }
            }
        }
        __syncthreads();
    }
    // final 4-way sum; thread t owns output p = t  (f_local = t>>4, il = t&15)
    return red[t] + red[1024 + t] + red[2048 + t] + red[3072 + t];
}

// mode M1: A = att bf16, B = XWT; out = M1T bf16 transposed (f-major)
__global__ __launch_bounds__(1024, 8) void gemm_fused_m1(
    const uint16_t* __restrict__ Aop, const uint16_t* __restrict__ Bop,
    uint16_t* __restrict__ M1T) {
    __shared__ __align__(16) float red[4 * 1024];
    const int i0 = blockIdx.x * 16, f0 = blockIdx.y * 64;
    const int t = threadIdx.x;
    const int lane = t & 63, wv = t >> 6;
    const int l16 = lane & 15, quad = lane >> 4;
    const int kBeg = wv * 256;

    f32x4 acc[4];
    #pragma unroll
    for (int ni = 0; ni < 4; ++ni) acc[ni] = (f32x4){0.f, 0.f, 0.f, 0.f};

    const uint16_t* Ap = Aop + (size_t)(i0 + l16) * NN + quad * 8;
    const uint16_t* Bp = Bop + (size_t)(f0 + l16) * NN + quad * 8;

    #pragma unroll
    for (int kk = 0; kk < 256; kk += 32) {
        const int k0 = kBeg + kk;
        const bf16x8 af = *(const bf16x8*)(Ap + k0);
        #pragma unroll
        for (int ni = 0; ni < 4; ++ni) {
            const bf16x8 bf = *(const bf16x8*)(Bp + (size_t)(ni * 16) * NN + k0);
            acc[ni] = __builtin_amdgcn_mfma_f32_16x16x32_bf16(af, bf, acc[ni], 0, 0, 0);
        }
    }
    const float v = gemm16_reduce64(red, acc);
    const int fl = t >> 4, il = t & 15;
    M1T[(size_t)(f0 + fl) * NN + i0 + il] = f2b(v);
}

// mode H: A = fp32 adjacency (converted in-register), B = M1T; out = H fp32
__global__ __launch_bounds__(1024, 8) void gemm_fused_h(
    const float* __restrict__ Aop, const uint16_t* __restrict__ Bop,
    float* __restrict__ H) {
    __shared__ __align__(16) float red[4 * 1024];
    __shared__ __align__(16) float lds2[16][68];
    const int i0 = blockIdx.x * 16, f0 = blockIdx.y * 64;
    const int t = threadIdx.x;
    const int lane = t & 63, wv = t >> 6;
    const int l16 = lane & 15, quad = lane >> 4;
    const int kBeg = wv * 256;

    f32x4 acc[4];
    #pragma unroll
    for (int ni = 0; ni < 4; ++ni) acc[ni] = (f32x4){0.f, 0.f, 0.f, 0.f};

    const float*    Ap = Aop + (size_t)(i0 + l16) * NN + quad * 8;
    const uint16_t* Bp = Bop + (size_t)(f0 + l16) * NN + quad * 8;

    #pragma unroll
    for (int kk = 0; kk < 256; kk += 32) {
        const int k0 = kBeg + kk;
        const float4 va = *(const float4*)(Ap + k0);
        const float4 vb = *(const float4*)(Ap + k0 + 4);
        union { uint16_t u[8]; bf16x8 v; } afu;
        afu.u[0] = f2b(va.x); afu.u[1] = f2b(va.y); afu.u[2] = f2b(va.z); afu.u[3] = f2b(va.w);
        afu.u[4] = f2b(vb.x); afu.u[5] = f2b(vb.y); afu.u[6] = f2b(vb.z); afu.u[7] = f2b(vb.w);
        const bf16x8 af = afu.v;
        #pragma unroll
        for (int ni = 0; ni < 4; ++ni) {
            const bf16x8 bf = *(const bf16x8*)(Bp + (size_t)(ni * 16) * NN + k0);
            acc[ni] = __builtin_amdgcn_mfma_f32_16x16x32_bf16(af, bf, acc[ni], 0, 0, 0);
        }
    }
    const float v = gemm16_reduce64(red, acc);
    const int fl = t >> 4, il = t & 15;
    lds2[il][fl] = v;
    __syncthreads();
    if (t < 256) {
        const int r = t >> 4, fq = t & 15;
        const float4 x = *(const float4*)(&lds2[r][fq * 4]);
        *(float4*)(H + (size_t)(i0 + r) * NF + f0 + fq * 4) = x;
    }
}

// ---------------------------------------------------------------------------
extern "C" void kernel_launch(void* const* d_in, const int* in_sizes, int n_in,
                              void* d_out, int out_size, void* d_ws, size_t ws_size,
                              hipStream_t stream) {
    (void)in_sizes; (void)n_in; (void)out_size; (void)ws_size;
    const float* X = (const float*)d_in[0];
    const float* A = (const float*)d_in[1];
    const float* W = (const float*)d_in[2];
    const float* a = (const float*)d_in[3];
    float* H = (float*)d_out;

    char* ws = (char*)d_ws;
    uint16_t* att = (uint16_t*)(ws + ((size_t)32 << 20));  // 32 MB bf16 att
    uint16_t* XWT = (uint16_t*)(ws + ((size_t)96 << 20));  // 1 MB
    uint16_t* M1T = (uint16_t*)(ws + ((size_t)97 << 20));  // 1 MB
    char* sm = ws + ((size_t)64 << 20);                    // small arrays
    float*  s_col = (float*) (sm);
    float*  s_row = (float*) (sm + (16 << 10));
    int*    ks    = (int*)   (sm + (32 << 10));
    float*  w1s   = (float*) (sm + (48 << 10));
    float*  w2s   = (float*) (sm + (64 << 10));
    float4* rec   = (float4*)(sm + (80 << 10));            // 64 KB {C, ec1, ec2, s_col}

    // 1. XW + scores (+ XWT bf16)
    xw_kernel<<<NN / XROWS, NF, 0, stream>>>(X, W, a, XWT, s_col, s_row);
    // 2. order statistics for the exact rank-1 decomposition of den
    prep_kernel<<<256, 256, 0, stream>>>(s_row, s_col, ks, w1s, w2s, rec);
    // 3. exact num + att per row via dual scan
    row_kernel<<<NN, 512, 0, stream>>>(A, s_row, ks, w1s, w2s, rec, att);
    // 4. M1T = (att @ XW)^T bf16 — f-split fused GEMM (512 blocks, 2/CU)
    gemm_fused_m1<<<dim3(256, 2), 1024, 0, stream>>>(att, XWT, M1T);
    // 5. H = A @ M1 — f-split fused GEMM, fp32 A converted in-register
    gemm_fused_h<<<dim3(256, 2), 1024, 0, stream>>>(A, M1T, H);
}

// Round 11
// 216.462 us; speedup vs baseline: 1.0441x; 1.0441x over previous
//
#include <hip/hip_runtime.h>
#include <hip/hip_bf16.h>
#include <stdint.h>

#define NN 4096
#define NF 128
#define XROWS 4

using f32x4  = __attribute__((ext_vector_type(4))) float;
using bf16x8 = __attribute__((ext_vector_type(8))) __bf16;
using u16x8  = __attribute__((ext_vector_type(8))) uint16_t;

__device__ __forceinline__ uint16_t f2b(float f) {
    union { float f; uint32_t u; } v; v.f = f;
    uint32_t r = v.u + 0x7FFFu + ((v.u >> 16) & 1u);
    return (uint16_t)(r >> 16);
}

__device__ __forceinline__ float b2f(uint16_t u) {
    union { uint32_t u; float f; } v; v.u = ((uint32_t)u) << 16;
    return v.f;
}

// ---------------------------------------------------------------------------
// Kernel 1: XW = X@W (4 rows/block), s_col/s_row scores, XWT bf16 (ushort4 store)
// ---------------------------------------------------------------------------
__global__ __launch_bounds__(128) void xw_kernel(
    const float* __restrict__ X, const float* __restrict__ W,
    const float* __restrict__ a,
    uint16_t* __restrict__ XWT,
    float* __restrict__ s_col, float* __restrict__ s_row) {
    __shared__ float xs[XROWS][NF];
    __shared__ float red[XROWS][2][2];
    const int i0 = blockIdx.x * XROWS, f = threadIdx.x;
    #pragma unroll
    for (int r = 0; r < XROWS; ++r) xs[r][f] = X[(size_t)(i0 + r) * NF + f];
    __syncthreads();
    float acc[XROWS] = {0.f, 0.f, 0.f, 0.f};
    #pragma unroll 4
    for (int k = 0; k < NF; ++k) {
        const float w = W[k * NF + f];
        #pragma unroll
        for (int r = 0; r < XROWS; ++r) acc[r] += xs[r][k] * w;
    }
    ushort4 xo;
    xo.x = f2b(acc[0]); xo.y = f2b(acc[1]); xo.z = f2b(acc[2]); xo.w = f2b(acc[3]);
    *(ushort4*)(XWT + (size_t)f * NN + i0) = xo;
    const float a1 = a[f], a2 = a[NF + f];
    #pragma unroll
    for (int r = 0; r < XROWS; ++r) {
        float sc = acc[r] * a1;
        float sr = acc[r] * a2;
        #pragma unroll
        for (int off = 32; off; off >>= 1) {
            sc += __shfl_down(sc, off);
            sr += __shfl_down(sr, off);
        }
        if ((f & 63) == 0) { red[r][f >> 6][0] = sc; red[r][f >> 6][1] = sr; }
    }
    __syncthreads();
    if (f < XROWS) {
        s_col[i0 + f] = red[f][0][0] + red[f][1][0];
        s_row[i0 + f] = red[f][0][1] + red[f][1][1];
    }
}

// ---------------------------------------------------------------------------
// Kernel 2: prep — brute-force order statistics (O(N^2) counting, fully parallel)
// ---------------------------------------------------------------------------
__global__ __launch_bounds__(256) void prep_kernel(
    const float* __restrict__ s_row, const float* __restrict__ s_col,
    int* __restrict__ ks, float* __restrict__ w1s, float* __restrict__ w2s,
    float4* __restrict__ rec) {
    __shared__ __align__(16) float sr[NN];
    const int t = threadIdx.x;
    #pragma unroll
    for (int c = 0; c < 16; ++c) sr[t + c * 256] = s_row[t + c * 256];
    __syncthreads();
    const bool isC = blockIdx.x >= 128;
    const int tgt = (blockIdx.x & 127) * 32 + (t >> 3);
    const int sub = t & 7;
    const float4* sr4 = (const float4*)sr;
    int cnt = 0;
    if (!isC) {
        const float s = sr[tgt];
        #pragma unroll 4
        for (int q = 0; q < 128; ++q) {
            const int k4 = q * 8 + sub;
            float4 v = sr4[k4];
            const int kb = k4 * 4;
            cnt += (v.x < s) | ((v.x == s) & (kb + 0 < tgt));
            cnt += (v.y < s) | ((v.y == s) & (kb + 1 < tgt));
            cnt += (v.z < s) | ((v.z == s) & (kb + 2 < tgt));
            cnt += (v.w < s) | ((v.w == s) & (kb + 3 < tgt));
        }
    } else {
        const float th = -s_col[tgt];
        #pragma unroll 4
        for (int q = 0; q < 128; ++q) {
            float4 v = sr4[q * 8 + sub];
            cnt += (v.x <= th) + (v.y <= th) + (v.z <= th) + (v.w <= th);
        }
    }
    cnt += __shfl_down(cnt, 4);
    cnt += __shfl_down(cnt, 2);
    cnt += __shfl_down(cnt, 1);
    if (sub == 0) {
        if (!isC) {
            const float s = sr[tgt];
            ks[cnt]  = tgt;
            w1s[cnt] = __expf(s);
            w2s[cnt] = __expf(0.01f * s);
        } else {
            const float sc = s_col[tgt];
            rec[tgt] = (float4){__int_as_float(cnt), __expf(sc), __expf(0.01f * sc), sc};
        }
    }
}

// ---------------------------------------------------------------------------
// Kernel 3: per-row exact num/att via dual scan (round-5 proven body,
// WITH bf16 A emission — both GEMMs consume bf16 A).
// ---------------------------------------------------------------------------
#define PB(b) ((b) + (((b) >> 4) << 1))

__global__ __launch_bounds__(512, 8) void row_kernel(
    const float* __restrict__ A,
    const float* __restrict__ s_row,
    const int* __restrict__ ks, const float* __restrict__ w1s, const float* __restrict__ w2s,
    const float4* __restrict__ rec,
    uint16_t* __restrict__ Ab, uint16_t* __restrict__ att) {
    __shared__ __align__(16) float rowA[NN];
    __shared__ __align__(16) uint16_t S1[4640];
    __shared__ __align__(16) uint16_t S2[4640];
    __shared__ float wtot[2][8];
    const int i = blockIdx.x, t = threadIdx.x;

    {
        const float4* Ar = (const float4*)(A + (size_t)i * NN);
        ushort4* Abr = (ushort4*)(Ab + (size_t)i * NN);
        #pragma unroll
        for (int c = 0; c < 2; ++c) {
            float4 v = Ar[t + c * 512];
            ((float4*)rowA)[t + c * 512] = v;
            ushort4 o; o.x = f2b(v.x); o.y = f2b(v.y); o.z = f2b(v.z); o.w = f2b(v.w);
            Abr[t + c * 512] = o;
        }
    }
    __syncthreads();

    float l1[8], l2[8];
    {
        const int4*   k4 = (const int4*)ks;
        const float4* a4 = (const float4*)w1s;
        const float4* b4 = (const float4*)w2s;
        float run1 = 0.f, run2 = 0.f;
        #pragma unroll
        for (int g = 0; g < 2; ++g) {
            int4   kk = k4[2 * t + g];
            float4 wa = a4[2 * t + g];
            float4 wb = b4[2 * t + g];
            float g0 = rowA[kk.x], g1 = rowA[kk.y], g2 = rowA[kk.z], g3 = rowA[kk.w];
            run1 += g0 * wa.x; l1[4 * g + 0] = run1;  run2 += g0 * wb.x; l2[4 * g + 0] = run2;
            run1 += g1 * wa.y; l1[4 * g + 1] = run1;  run2 += g1 * wb.y; l2[4 * g + 1] = run2;
            run1 += g2 * wa.z; l1[4 * g + 2] = run1;  run2 += g2 * wb.z; l2[4 * g + 2] = run2;
            run1 += g3 * wa.w; l1[4 * g + 3] = run1;  run2 += g3 * wb.w; l2[4 * g + 3] = run2;
        }
    }
    float s1 = l1[7], s2 = l2[7];
    const int lane = t & 63, wid = t >> 6;
    #pragma unroll
    for (int off = 1; off < 64; off <<= 1) {
        float u1 = __shfl_up(s1, off);
        float u2 = __shfl_up(s2, off);
        if (lane >= off) { s1 += u1; s2 += u2; }
    }
    if (lane == 63) { wtot[0][wid] = s1; wtot[1][wid] = s2; }
    __syncthreads();

    float off1 = 0.f, off2 = 0.f, tot1 = 0.f, tot2 = 0.f;
    #pragma unroll
    for (int w = 0; w < 8; ++w) {
        const float va = wtot[0][w], vb = wtot[1][w];
        tot1 += va; tot2 += vb;
        if (w < wid) { off1 += va; off2 += vb; }
    }
    const float ex1 = off1 + s1 - l1[7];
    const float ex2 = off2 + s2 - l2[7];
    {
        uint32_t* q1 = (uint32_t*)S1;
        uint32_t* q2 = (uint32_t*)S2;
        const int qb = t * 4 + (t >> 1);
        #pragma unroll
        for (int m = 0; m < 4; ++m) {
            const float pl1 = m ? l1[2 * m - 1] : 0.f;
            const float pl2 = m ? l2[2 * m - 1] : 0.f;
            const float sa = tot1 - ex1 - pl1;
            const float sb = tot1 - ex1 - l1[2 * m];
            const float pa = ex2 + pl2;
            const float pb = ex2 + l2[2 * m];
            q1[qb + m] = (uint32_t)f2b(sa) | ((uint32_t)f2b(sb) << 16);
            q2[qb + m] = (uint32_t)f2b(pa) | ((uint32_t)f2b(pb) << 16);
        }
    }
    if (t == 511) {
        S1[PB(4096)] = 0;
        S2[PB(4096)] = f2b(tot2);
    }
    __syncthreads();

    const float sri = s_row[i];
    uint32_t* attR = (uint32_t*)(att + (size_t)i * NN);
    #pragma unroll
    for (int e = 0; e < 4; ++e) {
        const int j0 = e * 1024 + 2 * t;
        const float4 ra = rec[j0];
        const float4 rb = rec[j0 + 1];
        const int Ca = __float_as_int(ra.x);
        const int Cb = __float_as_int(rb.x);
        const float numa = ra.y * b2f(S1[PB(Ca)]) + ra.z * b2f(S2[PB(Ca)]);
        const float numb = rb.y * b2f(S1[PB(Cb)]) + rb.z * b2f(S2[PB(Cb)]);
        float za = sri + ra.w; za = za > 0.f ? za : 0.01f * za;
        float zb = sri + rb.w; zb = zb > 0.f ? zb : 0.01f * zb;
        const float dena = __expf(za);
        const float denb = __expf(zb);
        const float va = (numa != 0.f) ? dena * __builtin_amdgcn_rcpf(numa) : 0.f;
        const float vb = (numb != 0.f) ? denb * __builtin_amdgcn_rcpf(numb) : 0.f;
        attR[e * 512 + t] = (uint32_t)f2b(va) | ((uint32_t)f2b(vb) << 16);
    }
}

// ---------------------------------------------------------------------------
// Kernels 4/5: fused skinny GEMM (round-8 geometry) + depth-2 register
// pipeline for MLP. grid 256, 1024 thr = 16 waves; wave w owns K-slice
// [w*256, +256) of the full 16x128 tile; 8 chunks of K=32.
// Named double buffers (a0/b0[8], a1/b1[8]) -> static indexing, ~116 VGPR;
// launch_bounds(1024,4) caps at 128.
// acc mapping (verified): row = quad*4+reg, col(frag) = ni*16 + l16.
// ---------------------------------------------------------------------------
#define G_LOAD(s, kq) {                                                       \
        a##s = *(const bf16x8*)(Ap + (kq));                                   \
        _Pragma("unroll")                                                     \
        for (int ni = 0; ni < 8; ++ni)                                        \
            b##s[ni] = *(const bf16x8*)(Bp + (size_t)(ni * 16) * NN + (kq));  \
    }

#define G_MFMA(s) {                                                           \
        _Pragma("unroll")                                                     \
        for (int ni = 0; ni < 8; ++ni)                                        \
            acc[ni] = __builtin_amdgcn_mfma_f32_16x16x32_bf16(                \
                a##s, b##s[ni], acc[ni], 0, 0, 0);                            \
    }

__device__ __forceinline__ void gemm16_reduce(
    float* __restrict__ red, const f32x4 acc[8], float2* __restrict__ v) {
    const int t = threadIdx.x;
    const int lane = t & 63, wv = t >> 6;
    const int l16 = lane & 15, quad = lane >> 4;
    float* img = red + (wv & 3) * 2048;
    const int base = l16 * 16 + quad * 4;
    #pragma unroll
    for (int ph = 0; ph < 4; ++ph) {
        if ((wv >> 2) == ph) {
            if (ph == 0) {
                #pragma unroll
                for (int ni = 0; ni < 8; ++ni)
                    *(f32x4*)(img + ni * 256 + base) = acc[ni];
            } else {
                #pragma unroll
                for (int ni = 0; ni < 8; ++ni) {
                    f32x4 x = *(const f32x4*)(img + ni * 256 + base);
                    *(f32x4*)(img + ni * 256 + base) = x + acc[ni];
                }
            }
        }
        __syncthreads();
    }
    float2 s = {0.f, 0.f};
    #pragma unroll
    for (int im = 0; im < 4; ++im) {
        const float2 x = *(const float2*)(red + im * 2048 + 2 * t);
        s.x += x.x; s.y += x.y;
    }
    *v = s;
}

// mode M1: A = att bf16, B = XWT; out = M1T bf16 transposed (f-major)
__global__ __launch_bounds__(1024, 4) void gemm_fused_m1(
    const uint16_t* __restrict__ Aop, const uint16_t* __restrict__ Bop,
    uint16_t* __restrict__ M1T) {
    __shared__ __align__(16) float red[4 * 2048];
    const int i0 = blockIdx.x * 16;
    const int t = threadIdx.x;
    const int lane = t & 63, wv = t >> 6;
    const int l16 = lane & 15, quad = lane >> 4;
    const int kBeg = wv * 256;

    f32x4 acc[8];
    #pragma unroll
    for (int ni = 0; ni < 8; ++ni) acc[ni] = (f32x4){0.f, 0.f, 0.f, 0.f};

    const uint16_t* Ap = Aop + (size_t)(i0 + l16) * NN + quad * 8;
    const uint16_t* Bp = Bop + (size_t)l16 * NN + quad * 8;

    bf16x8 a0, a1, b0[8], b1[8];
    G_LOAD(0, kBeg);
    #pragma unroll
    for (int kk = 0; kk < 256; kk += 64) {
        G_LOAD(1, kBeg + kk + 32);                    // prefetch odd chunk
        G_MFMA(0);                                    // compute even chunk
        if (kk + 64 < 256) G_LOAD(0, kBeg + kk + 64); // prefetch next even
        G_MFMA(1);                                    // compute odd chunk
    }

    float2 v;
    gemm16_reduce(red, acc, &v);
    const int p = 2 * t;
    const int f = p >> 4, il = p & 15;
    ushort2 o; o.x = f2b(v.x); o.y = f2b(v.y);
    *(ushort2*)(M1T + (size_t)f * NN + i0 + il) = o;
}

// mode H: A = Ab bf16, B = M1T; out = H fp32 row-major via LDS transpose
__global__ __launch_bounds__(1024, 4) void gemm_fused_h(
    const uint16_t* __restrict__ Aop, const uint16_t* __restrict__ Bop,
    float* __restrict__ H) {
    __shared__ __align__(16) float red[4 * 2048];
    __shared__ __align__(16) float lds2[16][132];
    const int i0 = blockIdx.x * 16;
    const int t = threadIdx.x;
    const int lane = t & 63, wv = t >> 6;
    const int l16 = lane & 15, quad = lane >> 4;
    const int kBeg = wv * 256;

    f32x4 acc[8];
    #pragma unroll
    for (int ni = 0; ni < 8; ++ni) acc[ni] = (f32x4){0.f, 0.f, 0.f, 0.f};

    const uint16_t* Ap = Aop + (size_t)(i0 + l16) * NN + quad * 8;
    const uint16_t* Bp = Bop + (size_t)l16 * NN + quad * 8;

    bf16x8 a0, a1, b0[8], b1[8];
    G_LOAD(0, kBeg);
    #pragma unroll
    for (int kk = 0; kk < 256; kk += 64) {
        G_LOAD(1, kBeg + kk + 32);
        G_MFMA(0);
        if (kk + 64 < 256) G_LOAD(0, kBeg + kk + 64);
        G_MFMA(1);
    }

    float2 v;
    gemm16_reduce(red, acc, &v);
    const int p = 2 * t;
    const int f = p >> 4, il = p & 15;
    lds2[il][f] = v.x;
    lds2[il + 1][f] = v.y;
    __syncthreads();
    if (t < 512) {
        const int r = t >> 5, fq = t & 31;
        const float4 x = *(const float4*)(&lds2[r][fq * 4]);
        *(float4*)(H + (size_t)(i0 + r) * NF + fq * 4) = x;
    }
}

// ---------------------------------------------------------------------------
extern "C" void kernel_launch(void* const* d_in, const int* in_sizes, int n_in,
                              void* d_out, int out_size, void* d_ws, size_t ws_size,
                              hipStream_t stream) {
    (void)in_sizes; (void)n_in; (void)out_size; (void)ws_size;
    const float* X = (const float*)d_in[0];
    const float* A = (const float*)d_in[1];
    const float* W = (const float*)d_in[2];
    const float* a = (const float*)d_in[3];
    float* H = (float*)d_out;

    char* ws = (char*)d_ws;
    uint16_t* Ab  = (uint16_t*)(ws);                       // 32 MB bf16 A
    uint16_t* att = (uint16_t*)(ws + ((size_t)32 << 20));  // 32 MB bf16 att
    uint16_t* XWT = (uint16_t*)(ws + ((size_t)96 << 20));  // 1 MB
    uint16_t* M1T = (uint16_t*)(ws + ((size_t)97 << 20));  // 1 MB
    char* sm = ws + ((size_t)64 << 20);                    // small arrays
    float*  s_col = (float*) (sm);
    float*  s_row = (float*) (sm + (16 << 10));
    int*    ks    = (int*)   (sm + (32 << 10));
    float*  w1s   = (float*) (sm + (48 << 10));
    float*  w2s   = (float*) (sm + (64 << 10));
    float4* rec   = (float4*)(sm + (80 << 10));            // 64 KB {C, ec1, ec2, s_col}

    // 1. XW + scores (+ XWT bf16)
    xw_kernel<<<NN / XROWS, NF, 0, stream>>>(X, W, a, XWT, s_col, s_row);
    // 2. order statistics for the exact rank-1 decomposition of den
    prep_kernel<<<256, 256, 0, stream>>>(s_row, s_col, ks, w1s, w2s, rec);
    // 3. exact num + att per row via dual scan (+ bf16 A copy)
    row_kernel<<<NN, 512, 0, stream>>>(A, s_row, ks, w1s, w2s, rec, Ab, att);
    // 4. M1T = (att @ XW)^T bf16 — fused GEMM, depth-2 register pipeline
    gemm_fused_m1<<<NN / 16, 1024, 0, stream>>>(att, XWT, M1T);
    // 5. H = Ab @ M1 — fused GEMM, depth-2 register pipeline
    gemm_fused_h<<<NN / 16, 1024, 0, stream>>>(Ab, M1T, H);
}